// Round 17
// baseline (696.723 us; speedup 1.0000x reference)
//
#include <hip/hip_runtime.h>

#define N_NODES 50000
#define N_EDGES 800000
#define DIM 128
#define EDGE_DIM 16
#define N_LAYERS 3
#define N_GRAPHS 64

// Async global->LDS. LDS dest = wave-uniform base + lane*size; global source
// address is PER-LANE.
__device__ __forceinline__ void gld_lds16(const float* g, float* l) {
    __builtin_amdgcn_global_load_lds(
        (__attribute__((address_space(1))) void*)(g),
        (__attribute__((address_space(3))) void*)(l), 16, 0, 0);
}
__device__ __forceinline__ void gld_lds4(const float* g, float* l) {
    __builtin_amdgcn_global_load_lds(
        (__attribute__((address_space(1))) void*)(g),
        (__attribute__((address_space(3))) void*)(l), 4, 0, 0);
}

// ---------------------------------------------------------------------------
// CSR build: histogram of dst -> exclusive scan -> scatter (src + ea permuted).
// ---------------------------------------------------------------------------
__global__ __launch_bounds__(256) void hist_kernel(
    const int* __restrict__ dst, int* __restrict__ row_ptr)
{
    const int e = blockIdx.x * 256 + threadIdx.x;
    if (e < N_EDGES) atomicAdd(&row_ptr[dst[e]], 1);
}

__global__ __launch_bounds__(1024) void scan_kernel(int* __restrict__ rp)
{
    __shared__ int sums[1024];
    const int t = threadIdx.x;
    const int chunk = (N_NODES + 1023) / 1024;   // 49
    const int lo = t * chunk;
    const int hi = min(lo + chunk, N_NODES);
    int s = 0;
    for (int j = lo; j < hi; ++j) s += rp[j];
    sums[t] = s;
    __syncthreads();
    for (int off = 1; off < 1024; off <<= 1) {
        int v = (t >= off) ? sums[t - off] : 0;
        __syncthreads();
        sums[t] += v;
        __syncthreads();
    }
    int run = (t == 0) ? 0 : sums[t - 1];        // exclusive prefix
    for (int j = lo; j < hi; ++j) {
        const int v = rp[j];
        rp[j] = run;
        run += v;
    }
    if (t == 1023) rp[N_NODES] = run;
}

__global__ __launch_bounds__(256) void scatter_kernel(
    const int* __restrict__ dst, const int* __restrict__ src,
    const float* __restrict__ ea,
    int* __restrict__ row_ptr,
    int* __restrict__ src_csr, float* __restrict__ ea_csr)
{
    const int e = blockIdx.x * 256 + threadIdx.x;
    if (e < N_EDGES) {
        const int pos = atomicAdd(&row_ptr[dst[e]], 1);
        src_csr[pos] = src[e];
        const float4* ap = reinterpret_cast<const float4*>(ea + (size_t)e * EDGE_DIM);
        float4* bp = reinterpret_cast<float4*>(ea_csr + (size_t)pos * EDGE_DIM);
        bp[0] = ap[0]; bp[1] = ap[1]; bp[2] = ap[2]; bp[3] = ap[3];
    }
    if (e < 16) src_csr[N_EDGES + e] = 0;   // pad: safe gather address
}

// ---------------------------------------------------------------------------
// Gather kernel (round-15 version, unchanged). One wave/node, 2 dims/lane.
// h pair-staged (one gld_lds16 stages two rows), ea staged, static A/B
// double buffers; src via int4 2 batches ahead; We hoisted to registers.
// ---------------------------------------------------------------------------
__global__ __launch_bounds__(256) void gather_kernel(
    const float* __restrict__ h,       // [N,128]
    const float* __restrict__ ea_csr,  // [E+8,16] CSR-permuted
    const int* __restrict__ src_csr,   // [E+16]   CSR-permuted, 16B-aligned
    const int* __restrict__ row_end,   // [N] end pointers
    const float* __restrict__ We,      // [16,128]
    const float* __restrict__ be,      // [128]
    float* __restrict__ z)             // [N,128]
{
    __shared__ float wsm[EDGE_DIM * DIM];   // 8 KB  We
    __shared__ float hbA[4][4 * DIM];       // 8 KB  h rows, batch buffer A
    __shared__ float hbB[4][4 * DIM];       // 8 KB  h rows, batch buffer B
    __shared__ float ebA[4][4 * EDGE_DIM];  // 1 KB  ea rows, buffer A
    __shared__ float ebB[4][4 * EDGE_DIM];  // 1 KB  ea rows, buffer B

    const int t = threadIdx.x;
#pragma unroll
    for (int i = 0; i < 8; ++i) wsm[i * 256 + t] = We[i * 256 + t];
    __syncthreads();

    const int lane = t & 63;
    const int wid  = t >> 6;
    const int n = blockIdx.x * 4 + wid;
    if (n >= N_NODES) return;
    const int d0 = 2 * lane;
    const bool hilane = lane >= 32;
    const int  lmod4  = (lane & 31) * 4;    // float offset within a row

    int vzero;
    asm volatile("v_mov_b32 %0, 0" : "=v"(vzero));   // opaque 0: vector path

    const float2* wl = reinterpret_cast<const float2*>(wsm);
    const float2 w0  = wl[0 * 64 + lane],  w1  = wl[1 * 64 + lane];
    const float2 w2  = wl[2 * 64 + lane],  w3  = wl[3 * 64 + lane];
    const float2 w4  = wl[4 * 64 + lane],  w5  = wl[5 * 64 + lane];
    const float2 w6  = wl[6 * 64 + lane],  w7  = wl[7 * 64 + lane];
    const float2 w8  = wl[8 * 64 + lane],  w9  = wl[9 * 64 + lane];
    const float2 w10 = wl[10 * 64 + lane], w11 = wl[11 * 64 + lane];
    const float2 w12 = wl[12 * 64 + lane], w13 = wl[13 * 64 + lane];
    const float2 w14 = wl[14 * 64 + lane], w15 = wl[15 * 64 + lane];
    const float2 bias = *reinterpret_cast<const float2*>(be + d0);

    const int beg = (n == 0) ? 0 : row_end[n - 1];
    const int end = row_end[n];

    float2 acc = *reinterpret_cast<const float2*>(h + (size_t)n * DIM + d0);

#define LOADSRC(S, IDX)                                                       \
    S = *(reinterpret_cast<const int4*>(src_csr + (IDX)) + vzero);

#define STAGE(HB, EB, IDX, S)                                                 \
    {                                                                         \
        const int s01 = hilane ? (S).y : (S).x;                               \
        const int s23 = hilane ? (S).w : (S).z;                               \
        gld_lds16(h + (size_t)s01 * DIM + lmod4, &HB[wid][0]);                \
        gld_lds16(h + (size_t)s23 * DIM + lmod4, &HB[wid][2 * DIM]);          \
        gld_lds4(ea_csr + (size_t)(IDX) * EDGE_DIM + lane, &EB[wid][0]);      \
    }

#define EF(C, WK)                                                             \
    tt.x = fmaf(C, WK.x, tt.x);                                               \
    tt.y = fmaf(C, WK.y, tt.y);

#define COMPUTE(HB, EB, IDX)                                                  \
    _Pragma("unroll")                                                         \
    for (int j = 0; j < 4; ++j) {                                             \
        const float2 hv = *reinterpret_cast<const float2*>(&HB[wid][j * DIM + d0]);        \
        const float4 a0 = *reinterpret_cast<const float4*>(&EB[wid][j * EDGE_DIM + 0]);    \
        const float4 a1 = *reinterpret_cast<const float4*>(&EB[wid][j * EDGE_DIM + 4]);    \
        const float4 a2 = *reinterpret_cast<const float4*>(&EB[wid][j * EDGE_DIM + 8]);    \
        const float4 a3 = *reinterpret_cast<const float4*>(&EB[wid][j * EDGE_DIM + 12]);   \
        float2 tt = bias;                                                     \
        EF(a0.x, w0)   EF(a0.y, w1)   EF(a0.z, w2)   EF(a0.w, w3)             \
        EF(a1.x, w4)   EF(a1.y, w5)   EF(a1.z, w6)   EF(a1.w, w7)             \
        EF(a2.x, w8)   EF(a2.y, w9)   EF(a2.z, w10)  EF(a2.w, w11)            \
        EF(a3.x, w12)  EF(a3.y, w13)  EF(a3.z, w14)  EF(a3.w, w15)            \
        const float mx = fmaxf(hv.x + tt.x, 0.0f);                            \
        const float my = fmaxf(hv.y + tt.y, 0.0f);                            \
        const bool ok = (unsigned)((IDX) + j - beg) < span;                   \
        acc.x += ok ? mx : 0.0f;                                              \
        acc.y += ok ? my : 0.0f;                                              \
    }

    if (beg < end) {
        const unsigned span = (unsigned)(end - beg);
        int idx = beg & ~3;                      // 16B-aligned batch start
        const int nb = (end - idx + 3) >> 2;
        int4 sA, sB;
        LOADSRC(sA, idx)                 // src batch 0 (one dwordx4)
        STAGE(hbA, ebA, idx, sA)         // stage batch 0 -> A
        LOADSRC(sB, idx + 4)             // src batch 1 (pad-safe)
        int i = 0;
        while (true) {
            // ---- batch i from A; stage i+1 -> B under A's compute ----
            if (i + 1 < nb) { STAGE(hbB, ebB, idx + 4, sB) }
            LOADSRC(sA, idx + 8)         // src for batch i+2 (pad-safe)
            COMPUTE(hbA, ebA, idx)
            ++i; idx += 4;
            if (i >= nb) break;
            // ---- batch i from B; stage i+1 -> A under B's compute ----
            if (i + 1 < nb) { STAGE(hbA, ebA, idx + 4, sA) }
            LOADSRC(sB, idx + 8)
            COMPUTE(hbB, ebB, idx)
            ++i; idx += 4;
            if (i >= nb) break;
        }
    }
#undef LOADSRC
#undef STAGE
#undef EF
#undef COMPUTE
    *reinterpret_cast<float2*>(z + (size_t)n * DIM + d0) = acc;
}

// ---------------------------------------------------------------------------
// Node MLP kernel: h_out = relu( relu(z@W1+b1) @ W2 + b2 )
// LDS-traffic-optimized: 64 nodes/block, 128 threads, acc[8][8]/thread
// (r0=(t>>4)*8, c0=(t&15)*8). Per k4 a thread loads 8 wv + 8 zv float4 for
// 1024 FMA -> 16 FMA per ds_read_b128 (was 10.7) -- node was LDS-issue-bound.
// BK=16 W k-tiles double-buffered via global_load_lds; LDS 48 KB -> 3 blk/CU.
// ---------------------------------------------------------------------------
__global__ __launch_bounds__(128) void node_kernel(
    const float* __restrict__ zin,   // [N,128]
    const float* __restrict__ W1,    // [128,128]
    const float* __restrict__ b1,    // [128]
    const float* __restrict__ W2,    // [128,128]
    const float* __restrict__ b2,    // [128]
    float* __restrict__ hout)        // [N,128]
{
    __shared__ float zt[64 * 128];   // 32 KB
    __shared__ float wt[2][16 * 128];// 2 x 8 KB, double-buffered W k-tile

    const int t = threadIdx.x;       // 0..127
    const int n0 = blockIdx.x * 64;
    const int c0 = (t & 15) * 8;     // 16 col-groups x 8 cols
    const int r0 = (t >> 4) * 8;     // 8 row-groups x 8 rows

    // stage tile 0 (W1, k-rows 0..15) into wt[0] — async (4 x 128 x 16B)
#pragma unroll
    for (int i = 0; i < 4; ++i) {
        const int f = (i * 128 + t) * 4;
        gld_lds16(W1 + f, &wt[0][f]);
    }

    // load z tile (coalesced float4; 16 per thread)
#pragma unroll
    for (int i = 0; i < 16; ++i) {
        const int f = (i * 128 + t) * 4;
        const int node = n0 + (f >> 7);
        const int dim = f & 127;
        float4 v = make_float4(0.f, 0.f, 0.f, 0.f);
        if (node < N_NODES)
            v = *reinterpret_cast<const float4*>(zin + (size_t)node * DIM + dim);
        *reinterpret_cast<float4*>(&zt[f]) = v;
    }

    const float4 bb1a = *reinterpret_cast<const float4*>(b1 + c0);
    const float4 bb1b = *reinterpret_cast<const float4*>(b1 + c0 + 4);
    const float4 bb2a = *reinterpret_cast<const float4*>(b2 + c0);
    const float4 bb2b = *reinterpret_cast<const float4*>(b2 + c0 + 4);

    float acc[8][8];
#pragma unroll
    for (int i = 0; i < 8; ++i)
#pragma unroll
        for (int j = 0; j < 8; ++j) acc[i][j] = 0.0f;

    __syncthreads();   // wt[0] DMA drained + zt visible

#define FMA8(ZC, K)                                                           \
    acc[i][0] = fmaf(ZC, wA[K].x, acc[i][0]);                                 \
    acc[i][1] = fmaf(ZC, wA[K].y, acc[i][1]);                                 \
    acc[i][2] = fmaf(ZC, wA[K].z, acc[i][2]);                                 \
    acc[i][3] = fmaf(ZC, wA[K].w, acc[i][3]);                                 \
    acc[i][4] = fmaf(ZC, wB[K].x, acc[i][4]);                                 \
    acc[i][5] = fmaf(ZC, wB[K].y, acc[i][5]);                                 \
    acc[i][6] = fmaf(ZC, wB[K].z, acc[i][6]);                                 \
    acc[i][7] = fmaf(ZC, wB[K].w, acc[i][7]);

    // tiles tt = 0..15: W1 k-tiles 0..7, then W2 k-tiles 0..7 (BK=16)
    for (int tt = 0; tt < 16; ++tt) {
        if (tt < 15) {
            const float* Wp = (tt + 1 < 8) ? W1 : W2;
            const int nk = (tt + 1) & 7;
            const int nb = (tt + 1) & 1;
#pragma unroll
            for (int i = 0; i < 4; ++i) {
                const int f = (i * 128 + t) * 4;
                gld_lds16(Wp + nk * 2048 + f, &wt[nb][f]);
            }
        }

        const int kk = tt & 7;
        const float* wts = wt[tt & 1];
#pragma unroll
        for (int k4 = 0; k4 < 4; ++k4) {
            const int kb = kk * 16 + k4 * 4;
            float4 wA[4], wB[4];
#pragma unroll
            for (int k = 0; k < 4; ++k) {
                wA[k] = *reinterpret_cast<const float4*>(&wts[(k4 * 4 + k) * 128 + c0]);
                wB[k] = *reinterpret_cast<const float4*>(&wts[(k4 * 4 + k) * 128 + c0 + 4]);
            }
#pragma unroll
            for (int i = 0; i < 8; ++i) {
                const float4 zv = *reinterpret_cast<const float4*>(&zt[(r0 + i) * 128 + kb]);
                FMA8(zv.x, 0)
                FMA8(zv.y, 1)
                FMA8(zv.z, 2)
                FMA8(zv.w, 3)
            }
        }
        __syncthreads();   // next tile landed; all reads of this phase done

        if (tt == 7) {
            // stage 1 done: write tmp = relu(acc+b1) into zt, reset acc
#pragma unroll
            for (int i = 0; i < 8; ++i) {
                float4 va = make_float4(fmaxf(acc[i][0] + bb1a.x, 0.f),
                                        fmaxf(acc[i][1] + bb1a.y, 0.f),
                                        fmaxf(acc[i][2] + bb1a.z, 0.f),
                                        fmaxf(acc[i][3] + bb1a.w, 0.f));
                float4 vb = make_float4(fmaxf(acc[i][4] + bb1b.x, 0.f),
                                        fmaxf(acc[i][5] + bb1b.y, 0.f),
                                        fmaxf(acc[i][6] + bb1b.z, 0.f),
                                        fmaxf(acc[i][7] + bb1b.w, 0.f));
                *reinterpret_cast<float4*>(&zt[(r0 + i) * 128 + c0]) = va;
                *reinterpret_cast<float4*>(&zt[(r0 + i) * 128 + c0 + 4]) = vb;
#pragma unroll
                for (int j = 0; j < 8; ++j) acc[i][j] = 0.0f;
            }
            __syncthreads();   // new zt visible before stage-2 compute
        }
    }
#undef FMA8

    // epilogue: h = relu(acc + b2)
#pragma unroll
    for (int i = 0; i < 8; ++i) {
        const int node = n0 + r0 + i;
        if (node < N_NODES) {
            float4 va = make_float4(fmaxf(acc[i][0] + bb2a.x, 0.f),
                                    fmaxf(acc[i][1] + bb2a.y, 0.f),
                                    fmaxf(acc[i][2] + bb2a.z, 0.f),
                                    fmaxf(acc[i][3] + bb2a.w, 0.f));
            float4 vb = make_float4(fmaxf(acc[i][4] + bb2b.x, 0.f),
                                    fmaxf(acc[i][5] + bb2b.y, 0.f),
                                    fmaxf(acc[i][6] + bb2b.z, 0.f),
                                    fmaxf(acc[i][7] + bb2b.w, 0.f));
            *reinterpret_cast<float4*>(hout + (size_t)node * DIM + c0) = va;
            *reinterpret_cast<float4*>(hout + (size_t)node * DIM + c0 + 4) = vb;
        }
    }
}

// ---------------------------------------------------------------------------
// Pool: batch is SORTED -> run-length accumulate, one atomic set per run.
// ---------------------------------------------------------------------------
__global__ __launch_bounds__(256) void pool_kernel(
    const float* __restrict__ h, const int* __restrict__ batch,
    float* __restrict__ gsum, float* __restrict__ cnt)
{
    const int lane = threadIdx.x & 63;
    const int wave = blockIdx.x * (blockDim.x >> 6) + (threadIdx.x >> 6);
    const int n0 = wave * 64;
    if (n0 >= N_NODES) return;
    const int n1 = min(n0 + 64, N_NODES);
    const int d0 = 2 * lane;

    int gcur = batch[n0];
    float2 acc = make_float2(0.f, 0.f);
    float c = 0.f;
    for (int n = n0; n < n1; ++n) {
        const int b = batch[n];
        if (b != gcur) {
            atomicAdd(&gsum[gcur * DIM + d0], acc.x);
            atomicAdd(&gsum[gcur * DIM + d0 + 1], acc.y);
            if (lane == 0) atomicAdd(&cnt[gcur], c);
            gcur = b; acc = make_float2(0.f, 0.f); c = 0.f;
        }
        const float2 hv = *reinterpret_cast<const float2*>(h + (size_t)n * DIM + d0);
        acc.x += hv.x; acc.y += hv.y; c += 1.f;
    }
    atomicAdd(&gsum[gcur * DIM + d0], acc.x);
    atomicAdd(&gsum[gcur * DIM + d0 + 1], acc.y);
    if (lane == 0) atomicAdd(&cnt[gcur], c);
}

// ---------------------------------------------------------------------------
// Readout: out[g] = relu(mean_g @ Wh1 + bh1) @ Wh2 + bh2.
// ---------------------------------------------------------------------------
__global__ __launch_bounds__(128) void readout_kernel(
    const float* __restrict__ gsum, const float* __restrict__ cnt,
    const float* __restrict__ Wh1, const float* __restrict__ bh1,
    const float* __restrict__ Wh2, const float* __restrict__ bh2,
    float* __restrict__ out)
{
    __shared__ float gv[128];
    __shared__ float partial[2];
    const int g = blockIdx.x;
    const int t = threadIdx.x;
    const float c = fmaxf(cnt[g], 1.0f);
    gv[t] = gsum[g * DIM + t] / c;
    __syncthreads();
    float acc = bh1[t];
    for (int k = 0; k < DIM; ++k)
        acc = fmaf(gv[k], Wh1[k * DIM + t], acc);
    float tv = fmaxf(acc, 0.0f) * Wh2[t];
    for (int off = 32; off > 0; off >>= 1) tv += __shfl_down(tv, off);
    if ((t & 63) == 0) partial[t >> 6] = tv;
    __syncthreads();
    if (t == 0) out[g] = partial[0] + partial[1] + bh2[0];
}

// ---------------------------------------------------------------------------
extern "C" void kernel_launch(void* const* d_in, const int* in_sizes, int n_in,
                              void* d_out, int out_size, void* d_ws, size_t ws_size,
                              hipStream_t stream) {
    const float* x         = (const float*)d_in[0];
    const int*   edge_idx  = (const int*)d_in[1];
    const int*   batch     = (const int*)d_in[2];
    const float* edge_attr = (const float*)d_in[3];
    const float* W1        = (const float*)d_in[4];
    const float* b1        = (const float*)d_in[5];
    const float* W2        = (const float*)d_in[6];
    const float* b2        = (const float*)d_in[7];
    const float* We        = (const float*)d_in[8];
    const float* be        = (const float*)d_in[9];
    const float* Wh1       = (const float*)d_in[10];
    const float* bh1       = (const float*)d_in[11];
    const float* Wh2       = (const float*)d_in[12];
    const float* bh2       = (const float*)d_in[13];
    float* out = (float*)d_out;

    const int* src = edge_idx;            // edge_index[0]
    const int* dst = edge_idx + N_EDGES;  // edge_index[1]

    float* ws = (float*)d_ws;
    float* h_ws    = ws;                                       // 50000*128 f
    float* z_ws    = h_ws + (size_t)N_NODES * DIM;             // 50000*128 f
    float* ea_csr  = z_ws + (size_t)N_NODES * DIM;             // (800000+8)*16 f
    float* gsum    = ea_csr + (size_t)(N_EDGES + 8) * EDGE_DIM;// 64*128 f
    float* cntf    = gsum + (size_t)N_GRAPHS * DIM;            // 64 f
    int*   row_ptr = (int*)(cntf + N_GRAPHS);                  // 50004 i (padded)
    int*   src_csr = row_ptr + (N_NODES + 4);                  // 800016 i, 16B-aligned

    // ---- CSR build (once per launch; reused by all 3 layers) ----
    hipMemsetAsync(row_ptr, 0, (N_NODES + 1) * sizeof(int), stream);
    hist_kernel<<<(N_EDGES + 255) / 256, 256, 0, stream>>>(dst, row_ptr);
    scan_kernel<<<1, 1024, 0, stream>>>(row_ptr);
    scatter_kernel<<<(N_EDGES + 255) / 256, 256, 0, stream>>>(
        dst, src, edge_attr, row_ptr, src_csr, ea_csr);

    // ---- layers ----
    const float* hin = x;
    for (int l = 0; l < N_LAYERS; ++l) {
        gather_kernel<<<(N_NODES + 3) / 4, 256, 0, stream>>>(
            hin, ea_csr, src_csr, row_ptr,
            We + (size_t)l * EDGE_DIM * DIM, be + (size_t)l * DIM, z_ws);
        node_kernel<<<(N_NODES + 63) / 64, 128, 0, stream>>>(
            z_ws,
            W1 + (size_t)l * DIM * DIM, b1 + (size_t)l * DIM,
            W2 + (size_t)l * DIM * DIM, b2 + (size_t)l * DIM,
            h_ws);
        hin = h_ws;
    }

    // ---- pool + readout ----
    hipMemsetAsync(gsum, 0, ((size_t)N_GRAPHS * DIM + N_GRAPHS) * sizeof(float), stream);
    pool_kernel<<<(N_NODES + 64 * 4 - 1) / (64 * 4), 256, 0, stream>>>(h_ws, batch, gsum, cntf);
    readout_kernel<<<N_GRAPHS, 128, 0, stream>>>(gsum, cntf, Wh1, bh1, Wh2, bh2, out);
}

// Round 18
// 654.511 us; speedup vs baseline: 1.0645x; 1.0645x over previous
//
#include <hip/hip_runtime.h>

#define N_NODES 50000
#define N_EDGES 800000
#define DIM 128
#define EDGE_DIM 16
#define N_LAYERS 3
#define N_GRAPHS 64

typedef float v2f __attribute__((ext_vector_type(2)));

// Packed fp32 FMA with op_sel broadcast of one W component to both halves.
// bx: d = (a.lo*w.lo+c.lo, a.hi*w.lo+c.hi)   [broadcast w.x]
__device__ __forceinline__ v2f pk_fma_bx(v2f a, v2f w, v2f c) {
    v2f d;
    asm("v_pk_fma_f32 %0, %1, %2, %3 op_sel:[0,0,0] op_sel_hi:[1,0,1]"
        : "=v"(d) : "v"(a), "v"(w), "v"(c));
    return d;
}
// by: d = (a.lo*w.hi+c.lo, a.hi*w.hi+c.hi)   [broadcast w.y]
__device__ __forceinline__ v2f pk_fma_by(v2f a, v2f w, v2f c) {
    v2f d;
    asm("v_pk_fma_f32 %0, %1, %2, %3 op_sel:[0,1,0] op_sel_hi:[1,1,1]"
        : "=v"(d) : "v"(a), "v"(w), "v"(c));
    return d;
}

// Async global->LDS. LDS dest = wave-uniform base + lane*size; global source
// address is PER-LANE.
__device__ __forceinline__ void gld_lds16(const float* g, float* l) {
    __builtin_amdgcn_global_load_lds(
        (__attribute__((address_space(1))) void*)(g),
        (__attribute__((address_space(3))) void*)(l), 16, 0, 0);
}
__device__ __forceinline__ void gld_lds4(const float* g, float* l) {
    __builtin_amdgcn_global_load_lds(
        (__attribute__((address_space(1))) void*)(g),
        (__attribute__((address_space(3))) void*)(l), 4, 0, 0);
}

// ---------------------------------------------------------------------------
// CSR build: histogram of dst -> exclusive scan -> scatter (src + ea permuted).
// ---------------------------------------------------------------------------
__global__ __launch_bounds__(256) void hist_kernel(
    const int* __restrict__ dst, int* __restrict__ row_ptr)
{
    const int e = blockIdx.x * 256 + threadIdx.x;
    if (e < N_EDGES) atomicAdd(&row_ptr[dst[e]], 1);
}

__global__ __launch_bounds__(1024) void scan_kernel(int* __restrict__ rp)
{
    __shared__ int sums[1024];
    const int t = threadIdx.x;
    const int chunk = (N_NODES + 1023) / 1024;   // 49
    const int lo = t * chunk;
    const int hi = min(lo + chunk, N_NODES);
    int s = 0;
    for (int j = lo; j < hi; ++j) s += rp[j];
    sums[t] = s;
    __syncthreads();
    for (int off = 1; off < 1024; off <<= 1) {
        int v = (t >= off) ? sums[t - off] : 0;
        __syncthreads();
        sums[t] += v;
        __syncthreads();
    }
    int run = (t == 0) ? 0 : sums[t - 1];        // exclusive prefix
    for (int j = lo; j < hi; ++j) {
        const int v = rp[j];
        rp[j] = run;
        run += v;
    }
    if (t == 1023) rp[N_NODES] = run;
}

__global__ __launch_bounds__(256) void scatter_kernel(
    const int* __restrict__ dst, const int* __restrict__ src,
    const float* __restrict__ ea,
    int* __restrict__ row_ptr,
    int* __restrict__ src_csr, float* __restrict__ ea_csr)
{
    const int e = blockIdx.x * 256 + threadIdx.x;
    if (e < N_EDGES) {
        const int pos = atomicAdd(&row_ptr[dst[e]], 1);
        src_csr[pos] = src[e];
        const float4* ap = reinterpret_cast<const float4*>(ea + (size_t)e * EDGE_DIM);
        float4* bp = reinterpret_cast<float4*>(ea_csr + (size_t)pos * EDGE_DIM);
        bp[0] = ap[0]; bp[1] = ap[1]; bp[2] = ap[2]; bp[3] = ap[3];
    }
    if (e < 16) src_csr[N_EDGES + e] = 0;   // pad: safe gather address
}

// ---------------------------------------------------------------------------
// Gather kernel. One wave/node, 2 dims/lane. h pair-staged via gld_lds16
// (one instr stages two rows), ea staged (k,j)-TRANSPOSED via per-lane
// source address so (ea[e0][k], ea[e1][k]) are LDS-adjacent -> ds_read_b64
// feeds v_pk_fma_f32 directly. op_sel broadcasts w.x/w.y -> 64 pk_fma per
// batch replace 128 scalar fma. Static A/B double buffers; COMPUTE consumes
// LDS only (counted vmcnt keeps staging in flight); src int4 2 batches ahead.
// ---------------------------------------------------------------------------
__global__ __launch_bounds__(256) void gather_kernel(
    const float* __restrict__ h,       // [N,128]
    const float* __restrict__ ea_csr,  // [E+8,16] CSR-permuted
    const int* __restrict__ src_csr,   // [E+16]   CSR-permuted, 16B-aligned
    const int* __restrict__ row_end,   // [N] end pointers
    const float* __restrict__ We,      // [16,128]
    const float* __restrict__ be,      // [128]
    float* __restrict__ z)             // [N,128]
{
    __shared__ float wsm[EDGE_DIM * DIM];   // 8 KB  We
    __shared__ float hbA[4][4 * DIM];       // 8 KB  h rows, batch buffer A
    __shared__ float hbB[4][4 * DIM];       // 8 KB  h rows, batch buffer B
    __shared__ float ebA[4][4 * EDGE_DIM];  // 1 KB  ea rows (k-major), buf A
    __shared__ float ebB[4][4 * EDGE_DIM];  // 1 KB  ea rows (k-major), buf B

    const int t = threadIdx.x;
#pragma unroll
    for (int i = 0; i < 8; ++i) wsm[i * 256 + t] = We[i * 256 + t];
    __syncthreads();

    const int lane = t & 63;
    const int wid  = t >> 6;
    const int n = blockIdx.x * 4 + wid;
    if (n >= N_NODES) return;
    const int d0 = 2 * lane;
    const bool hilane = lane >= 32;
    const int  lmod4  = (lane & 31) * 4;               // float offset in a row
    const int  ealoff = (lane & 3) * EDGE_DIM + (lane >> 2); // (k,j)-transpose

    int vzero;
    asm volatile("v_mov_b32 %0, 0" : "=v"(vzero));     // opaque 0: vector path

    v2f wv[16];
#pragma unroll
    for (int k = 0; k < 16; ++k)
        wv[k] = *reinterpret_cast<const v2f*>(&wsm[k * DIM + d0]);
    const float2 bias = *reinterpret_cast<const float2*>(be + d0);
    const v2f biasxx = {bias.x, bias.x};
    const v2f biasyy = {bias.y, bias.y};

    const int beg = (n == 0) ? 0 : row_end[n - 1];
    const int end = row_end[n];

    float2 acc = *reinterpret_cast<const float2*>(h + (size_t)n * DIM + d0);

#define LOADSRC(S, IDX)                                                       \
    S = *(reinterpret_cast<const int4*>(src_csr + (IDX)) + vzero);

#define STAGE(HB, EB, IDX, S)                                                 \
    {                                                                         \
        const int s01 = hilane ? (S).y : (S).x;                               \
        const int s23 = hilane ? (S).w : (S).z;                               \
        gld_lds16(h + (size_t)s01 * DIM + lmod4, &HB[wid][0]);                \
        gld_lds16(h + (size_t)s23 * DIM + lmod4, &HB[wid][2 * DIM]);          \
        gld_lds4(ea_csr + (size_t)(IDX) * EDGE_DIM + ealoff, &EB[wid][0]);    \
    }

#define PAIR(HB, EB, J0, IDX)                                                 \
    {                                                                         \
        v2f ttx = biasxx, tty = biasyy;                                       \
        _Pragma("unroll")                                                     \
        for (int k = 0; k < 16; ++k) {                                        \
            const v2f ap = *reinterpret_cast<const v2f*>(                     \
                &EB[wid][k * 4 + (J0)]);                                      \
            ttx = pk_fma_bx(ap, wv[k], ttx);                                  \
            tty = pk_fma_by(ap, wv[k], tty);                                  \
        }                                                                     \
        const float* hb = &HB[wid][(J0) * DIM + d0];                          \
        const float2 h0 = *reinterpret_cast<const float2*>(hb);               \
        const float2 h1 = *reinterpret_cast<const float2*>(hb + DIM);         \
        const bool ok0 = (unsigned)((IDX) + (J0) - beg) < span;               \
        const bool ok1 = (unsigned)((IDX) + (J0) + 1 - beg) < span;           \
        acc.x += ok0 ? fmaxf(h0.x + ttx[0], 0.f) : 0.f;                       \
        acc.y += ok0 ? fmaxf(h0.y + tty[0], 0.f) : 0.f;                       \
        acc.x += ok1 ? fmaxf(h1.x + ttx[1], 0.f) : 0.f;                       \
        acc.y += ok1 ? fmaxf(h1.y + tty[1], 0.f) : 0.f;                       \
    }

#define COMPUTE(HB, EB, IDX) PAIR(HB, EB, 0, IDX) PAIR(HB, EB, 2, IDX)

    if (beg < end) {
        const unsigned span = (unsigned)(end - beg);
        int idx = beg & ~3;                      // 16B-aligned batch start
        const int nb = (end - idx + 3) >> 2;
        int4 sA, sB;
        LOADSRC(sA, idx)                 // src batch 0 (one dwordx4)
        STAGE(hbA, ebA, idx, sA)         // stage batch 0 -> A
        LOADSRC(sB, idx + 4)             // src batch 1 (pad-safe)
        int i = 0;
        while (true) {
            // ---- batch i from A; stage i+1 -> B under A's compute ----
            if (i + 1 < nb) { STAGE(hbB, ebB, idx + 4, sB) }
            LOADSRC(sA, idx + 8)         // src for batch i+2 (pad-safe)
            COMPUTE(hbA, ebA, idx)
            ++i; idx += 4;
            if (i >= nb) break;
            // ---- batch i from B; stage i+1 -> A under B's compute ----
            if (i + 1 < nb) { STAGE(hbA, ebA, idx + 4, sA) }
            LOADSRC(sB, idx + 8)
            COMPUTE(hbB, ebB, idx)
            ++i; idx += 4;
            if (i >= nb) break;
        }
    }
#undef LOADSRC
#undef STAGE
#undef PAIR
#undef COMPUTE
    *reinterpret_cast<float2*>(z + (size_t)n * DIM + d0) = acc;
}

// ---------------------------------------------------------------------------
// Node MLP kernel (best-measured config from the 640us run): 64 nodes/block,
// 256 threads, acc[8][4], BK=32 W k-tiles double-buffered via global_load_lds,
// zt read as float4 along k (k4-grouping).
// ---------------------------------------------------------------------------
__global__ __launch_bounds__(256) void node_kernel(
    const float* __restrict__ zin,   // [N,128]
    const float* __restrict__ W1,    // [128,128]
    const float* __restrict__ b1,    // [128]
    const float* __restrict__ W2,    // [128,128]
    const float* __restrict__ b2,    // [128]
    float* __restrict__ hout)        // [N,128]
{
    __shared__ float zt[64 * 128];   // 32 KB
    __shared__ float wt[2][32 * 128];// 2 x 16 KB, double-buffered W k-tile

    const int t = threadIdx.x;
    const int n0 = blockIdx.x * 64;
    const int c0 = (t & 31) * 4;
    const int r0 = (t >> 5) * 8;

    // stage tile 0 (W1, k-tile 0) into wt[0] — async
#pragma unroll
    for (int i = 0; i < 4; ++i) {
        const int f = (i * 256 + t) * 4;
        gld_lds16(W1 + f, &wt[0][f]);
    }

    // load z tile (coalesced float4)
#pragma unroll
    for (int i = 0; i < 8; ++i) {
        const int f = (i * 256 + t) * 4;
        const int node = n0 + (f >> 7);
        const int dim = f & 127;
        float4 v = make_float4(0.f, 0.f, 0.f, 0.f);
        if (node < N_NODES)
            v = *reinterpret_cast<const float4*>(zin + (size_t)node * DIM + dim);
        *reinterpret_cast<float4*>(&zt[f]) = v;
    }

    const float4 bb1 = *reinterpret_cast<const float4*>(b1 + c0);
    const float4 bb2 = *reinterpret_cast<const float4*>(b2 + c0);

    float acc[8][4];
#pragma unroll
    for (int i = 0; i < 8; ++i)
#pragma unroll
        for (int j = 0; j < 4; ++j) acc[i][j] = 0.0f;

    __syncthreads();   // wt[0] DMA drained + zt visible

    // tiles tt = 0..7: W1 k-tiles 0..3, then W2 k-tiles 0..3
    for (int tt = 0; tt < 8; ++tt) {
        if (tt < 7) {
            const float* Wp = (tt + 1 < 4) ? W1 : W2;
            const int nk = (tt + 1) & 3;
            const int nb = (tt + 1) & 1;
#pragma unroll
            for (int i = 0; i < 4; ++i) {
                const int f = (i * 256 + t) * 4;
                gld_lds16(Wp + nk * 4096 + f, &wt[nb][f]);
            }
        }

        const int kk = tt & 3;
        const float* wts = wt[tt & 1];
#pragma unroll
        for (int k4 = 0; k4 < 8; ++k4) {
            const int kb = kk * 32 + k4 * 4;
            const float4 wv0 = *reinterpret_cast<const float4*>(&wts[(k4 * 4 + 0) * 128 + c0]);
            const float4 wv1 = *reinterpret_cast<const float4*>(&wts[(k4 * 4 + 1) * 128 + c0]);
            const float4 wv2 = *reinterpret_cast<const float4*>(&wts[(k4 * 4 + 2) * 128 + c0]);
            const float4 wv3 = *reinterpret_cast<const float4*>(&wts[(k4 * 4 + 3) * 128 + c0]);
#pragma unroll
            for (int i = 0; i < 8; ++i) {
                const float4 zv = *reinterpret_cast<const float4*>(&zt[(r0 + i) * 128 + kb]);
                acc[i][0] = fmaf(zv.x, wv0.x, acc[i][0]);
                acc[i][1] = fmaf(zv.x, wv0.y, acc[i][1]);
                acc[i][2] = fmaf(zv.x, wv0.z, acc[i][2]);
                acc[i][3] = fmaf(zv.x, wv0.w, acc[i][3]);
                acc[i][0] = fmaf(zv.y, wv1.x, acc[i][0]);
                acc[i][1] = fmaf(zv.y, wv1.y, acc[i][1]);
                acc[i][2] = fmaf(zv.y, wv1.z, acc[i][2]);
                acc[i][3] = fmaf(zv.y, wv1.w, acc[i][3]);
                acc[i][0] = fmaf(zv.z, wv2.x, acc[i][0]);
                acc[i][1] = fmaf(zv.z, wv2.y, acc[i][1]);
                acc[i][2] = fmaf(zv.z, wv2.z, acc[i][2]);
                acc[i][3] = fmaf(zv.z, wv2.w, acc[i][3]);
                acc[i][0] = fmaf(zv.w, wv3.x, acc[i][0]);
                acc[i][1] = fmaf(zv.w, wv3.y, acc[i][1]);
                acc[i][2] = fmaf(zv.w, wv3.z, acc[i][2]);
                acc[i][3] = fmaf(zv.w, wv3.w, acc[i][3]);
            }
        }
        __syncthreads();   // next tile landed; all reads of this phase done

        if (tt == 3) {
#pragma unroll
            for (int i = 0; i < 8; ++i) {
                float4 v = make_float4(fmaxf(acc[i][0] + bb1.x, 0.f),
                                       fmaxf(acc[i][1] + bb1.y, 0.f),
                                       fmaxf(acc[i][2] + bb1.z, 0.f),
                                       fmaxf(acc[i][3] + bb1.w, 0.f));
                *reinterpret_cast<float4*>(&zt[(r0 + i) * 128 + c0]) = v;
#pragma unroll
                for (int j = 0; j < 4; ++j) acc[i][j] = 0.0f;
            }
            __syncthreads();   // new zt visible before stage-2 compute
        }
    }

    // epilogue: h = relu(acc + b2)
#pragma unroll
    for (int i = 0; i < 8; ++i) {
        const int node = n0 + r0 + i;
        if (node < N_NODES) {
            float4 v = make_float4(fmaxf(acc[i][0] + bb2.x, 0.f),
                                   fmaxf(acc[i][1] + bb2.y, 0.f),
                                   fmaxf(acc[i][2] + bb2.z, 0.f),
                                   fmaxf(acc[i][3] + bb2.w, 0.f));
            *reinterpret_cast<float4*>(hout + (size_t)node * DIM + c0) = v;
        }
    }
}

// ---------------------------------------------------------------------------
// Pool: batch is SORTED -> run-length accumulate, one atomic set per run.
// ---------------------------------------------------------------------------
__global__ __launch_bounds__(256) void pool_kernel(
    const float* __restrict__ h, const int* __restrict__ batch,
    float* __restrict__ gsum, float* __restrict__ cnt)
{
    const int lane = threadIdx.x & 63;
    const int wave = blockIdx.x * (blockDim.x >> 6) + (threadIdx.x >> 6);
    const int n0 = wave * 64;
    if (n0 >= N_NODES) return;
    const int n1 = min(n0 + 64, N_NODES);
    const int d0 = 2 * lane;

    int gcur = batch[n0];
    float2 acc = make_float2(0.f, 0.f);
    float c = 0.f;
    for (int n = n0; n < n1; ++n) {
        const int b = batch[n];
        if (b != gcur) {
            atomicAdd(&gsum[gcur * DIM + d0], acc.x);
            atomicAdd(&gsum[gcur * DIM + d0 + 1], acc.y);
            if (lane == 0) atomicAdd(&cnt[gcur], c);
            gcur = b; acc = make_float2(0.f, 0.f); c = 0.f;
        }
        const float2 hv = *reinterpret_cast<const float2*>(h + (size_t)n * DIM + d0);
        acc.x += hv.x; acc.y += hv.y; c += 1.f;
    }
    atomicAdd(&gsum[gcur * DIM + d0], acc.x);
    atomicAdd(&gsum[gcur * DIM + d0 + 1], acc.y);
    if (lane == 0) atomicAdd(&cnt[gcur], c);
}

// ---------------------------------------------------------------------------
// Readout: out[g] = relu(mean_g @ Wh1 + bh1) @ Wh2 + bh2.
// ---------------------------------------------------------------------------
__global__ __launch_bounds__(128) void readout_kernel(
    const float* __restrict__ gsum, const float* __restrict__ cnt,
    const float* __restrict__ Wh1, const float* __restrict__ bh1,
    const float* __restrict__ Wh2, const float* __restrict__ bh2,
    float* __restrict__ out)
{
    __shared__ float gv[128];
    __shared__ float partial[2];
    const int g = blockIdx.x;
    const int t = threadIdx.x;
    const float c = fmaxf(cnt[g], 1.0f);
    gv[t] = gsum[g * DIM + t] / c;
    __syncthreads();
    float acc = bh1[t];
    for (int k = 0; k < DIM; ++k)
        acc = fmaf(gv[k], Wh1[k * DIM + t], acc);
    float tv = fmaxf(acc, 0.0f) * Wh2[t];
    for (int off = 32; off > 0; off >>= 1) tv += __shfl_down(tv, off);
    if ((t & 63) == 0) partial[t >> 6] = tv;
    __syncthreads();
    if (t == 0) out[g] = partial[0] + partial[1] + bh2[0];
}

// ---------------------------------------------------------------------------
extern "C" void kernel_launch(void* const* d_in, const int* in_sizes, int n_in,
                              void* d_out, int out_size, void* d_ws, size_t ws_size,
                              hipStream_t stream) {
    const float* x         = (const float*)d_in[0];
    const int*   edge_idx  = (const int*)d_in[1];
    const int*   batch     = (const int*)d_in[2];
    const float* edge_attr = (const float*)d_in[3];
    const float* W1        = (const float*)d_in[4];
    const float* b1        = (const float*)d_in[5];
    const float* W2        = (const float*)d_in[6];
    const float* b2        = (const float*)d_in[7];
    const float* We        = (const float*)d_in[8];
    const float* be        = (const float*)d_in[9];
    const float* Wh1       = (const float*)d_in[10];
    const float* bh1       = (const float*)d_in[11];
    const float* Wh2       = (const float*)d_in[12];
    const float* bh2       = (const float*)d_in[13];
    float* out = (float*)d_out;

    const int* src = edge_idx;            // edge_index[0]
    const int* dst = edge_idx + N_EDGES;  // edge_index[1]

    float* ws = (float*)d_ws;
    float* h_ws    = ws;                                       // 50000*128 f
    float* z_ws    = h_ws + (size_t)N_NODES * DIM;             // 50000*128 f
    float* ea_csr  = z_ws + (size_t)N_NODES * DIM;             // (800000+8)*16 f
    float* gsum    = ea_csr + (size_t)(N_EDGES + 8) * EDGE_DIM;// 64*128 f
    float* cntf    = gsum + (size_t)N_GRAPHS * DIM;            // 64 f
    int*   row_ptr = (int*)(cntf + N_GRAPHS);                  // 50004 i (padded)
    int*   src_csr = row_ptr + (N_NODES + 4);                  // 800016 i, 16B-aligned

    // ---- CSR build (once per launch; reused by all 3 layers) ----
    hipMemsetAsync(row_ptr, 0, (N_NODES + 1) * sizeof(int), stream);
    hist_kernel<<<(N_EDGES + 255) / 256, 256, 0, stream>>>(dst, row_ptr);
    scan_kernel<<<1, 1024, 0, stream>>>(row_ptr);
    scatter_kernel<<<(N_EDGES + 255) / 256, 256, 0, stream>>>(
        dst, src, edge_attr, row_ptr, src_csr, ea_csr);

    // ---- layers ----
    const float* hin = x;
    for (int l = 0; l < N_LAYERS; ++l) {
        gather_kernel<<<(N_NODES + 3) / 4, 256, 0, stream>>>(
            hin, ea_csr, src_csr, row_ptr,
            We + (size_t)l * EDGE_DIM * DIM, be + (size_t)l * DIM, z_ws);
        node_kernel<<<(N_NODES + 63) / 64, 256, 0, stream>>>(
            z_ws,
            W1 + (size_t)l * DIM * DIM, b1 + (size_t)l * DIM,
            W2 + (size_t)l * DIM * DIM, b2 + (size_t)l * DIM,
            h_ws);
        hin = h_ws;
    }

    // ---- pool + readout ----
    hipMemsetAsync(gsum, 0, ((size_t)N_GRAPHS * DIM + N_GRAPHS) * sizeof(float), stream);
    pool_kernel<<<(N_NODES + 64 * 4 - 1) / (64 * 4), 256, 0, stream>>>(h_ws, batch, gsum, cntf);
    readout_kernel<<<N_GRAPHS, 128, 0, stream>>>(gsum, cntf, Wh1, bh1, Wh2, bh2, out);
}

// Round 19
// 639.304 us; speedup vs baseline: 1.0898x; 1.0238x over previous
//
#include <hip/hip_runtime.h>

#define N_NODES 50000
#define N_EDGES 800000
#define DIM 128
#define EDGE_DIM 16
#define N_LAYERS 3
#define N_GRAPHS 64

// Async global->LDS. LDS dest = wave-uniform base + lane*size; global source
// address is PER-LANE.
__device__ __forceinline__ void gld_lds16(const float* g, float* l) {
    __builtin_amdgcn_global_load_lds(
        (__attribute__((address_space(1))) void*)(g),
        (__attribute__((address_space(3))) void*)(l), 16, 0, 0);
}
__device__ __forceinline__ void gld_lds4(const float* g, float* l) {
    __builtin_amdgcn_global_load_lds(
        (__attribute__((address_space(1))) void*)(g),
        (__attribute__((address_space(3))) void*)(l), 4, 0, 0);
}

// ---------------------------------------------------------------------------
// CSR build: histogram of dst -> exclusive scan -> scatter (src + ea permuted).
// ---------------------------------------------------------------------------
__global__ __launch_bounds__(256) void hist_kernel(
    const int* __restrict__ dst, int* __restrict__ row_ptr)
{
    const int e = blockIdx.x * 256 + threadIdx.x;
    if (e < N_EDGES) atomicAdd(&row_ptr[dst[e]], 1);
}

__global__ __launch_bounds__(1024) void scan_kernel(int* __restrict__ rp)
{
    __shared__ int sums[1024];
    const int t = threadIdx.x;
    const int chunk = (N_NODES + 1023) / 1024;   // 49
    const int lo = t * chunk;
    const int hi = min(lo + chunk, N_NODES);
    int s = 0;
    for (int j = lo; j < hi; ++j) s += rp[j];
    sums[t] = s;
    __syncthreads();
    for (int off = 1; off < 1024; off <<= 1) {
        int v = (t >= off) ? sums[t - off] : 0;
        __syncthreads();
        sums[t] += v;
        __syncthreads();
    }
    int run = (t == 0) ? 0 : sums[t - 1];        // exclusive prefix
    for (int j = lo; j < hi; ++j) {
        const int v = rp[j];
        rp[j] = run;
        run += v;
    }
    if (t == 1023) rp[N_NODES] = run;
}

__global__ __launch_bounds__(256) void scatter_kernel(
    const int* __restrict__ dst, const int* __restrict__ src,
    const float* __restrict__ ea,
    int* __restrict__ row_ptr,
    int* __restrict__ src_csr, float* __restrict__ ea_csr)
{
    const int e = blockIdx.x * 256 + threadIdx.x;
    if (e < N_EDGES) {
        const int pos = atomicAdd(&row_ptr[dst[e]], 1);
        src_csr[pos] = src[e];
        const float4* ap = reinterpret_cast<const float4*>(ea + (size_t)e * EDGE_DIM);
        float4* bp = reinterpret_cast<float4*>(ea_csr + (size_t)pos * EDGE_DIM);
        bp[0] = ap[0]; bp[1] = ap[1]; bp[2] = ap[2]; bp[3] = ap[3];
    }
    if (e < 16) src_csr[N_EDGES + e] = 0;   // pad: safe gather address
}

// ---------------------------------------------------------------------------
// Gather kernel (best-measured: 100 us/dispatch, VALUBusy 85%, 0 bank
// conflicts). One wave/node, 2 dims/lane. h pair-staged via gld_lds16 (one
// instr stages two rows: lanes 0-31 row A, 32-63 row B), ea staged row-major,
// static A/B double buffers (COMPUTE consumes LDS only -> counted vmcnt keeps
// staging in flight); src via one int4 load, 2 batches ahead; We in registers.
// ---------------------------------------------------------------------------
__global__ __launch_bounds__(256) void gather_kernel(
    const float* __restrict__ h,       // [N,128]
    const float* __restrict__ ea_csr,  // [E+8,16] CSR-permuted
    const int* __restrict__ src_csr,   // [E+16]   CSR-permuted, 16B-aligned
    const int* __restrict__ row_end,   // [N] end pointers
    const float* __restrict__ We,      // [16,128]
    const float* __restrict__ be,      // [128]
    float* __restrict__ z)             // [N,128]
{
    __shared__ float wsm[EDGE_DIM * DIM];   // 8 KB  We
    __shared__ float hbA[4][4 * DIM];       // 8 KB  h rows, batch buffer A
    __shared__ float hbB[4][4 * DIM];       // 8 KB  h rows, batch buffer B
    __shared__ float ebA[4][4 * EDGE_DIM];  // 1 KB  ea rows, buffer A
    __shared__ float ebB[4][4 * EDGE_DIM];  // 1 KB  ea rows, buffer B

    const int t = threadIdx.x;
#pragma unroll
    for (int i = 0; i < 8; ++i) wsm[i * 256 + t] = We[i * 256 + t];
    __syncthreads();

    const int lane = t & 63;
    const int wid  = t >> 6;
    const int n = blockIdx.x * 4 + wid;
    if (n >= N_NODES) return;
    const int d0 = 2 * lane;
    const bool hilane = lane >= 32;
    const int  lmod4  = (lane & 31) * 4;    // float offset within a row

    int vzero;
    asm volatile("v_mov_b32 %0, 0" : "=v"(vzero));   // opaque 0: vector path

    const float2* wl = reinterpret_cast<const float2*>(wsm);
    const float2 w0  = wl[0 * 64 + lane],  w1  = wl[1 * 64 + lane];
    const float2 w2  = wl[2 * 64 + lane],  w3  = wl[3 * 64 + lane];
    const float2 w4  = wl[4 * 64 + lane],  w5  = wl[5 * 64 + lane];
    const float2 w6  = wl[6 * 64 + lane],  w7  = wl[7 * 64 + lane];
    const float2 w8  = wl[8 * 64 + lane],  w9  = wl[9 * 64 + lane];
    const float2 w10 = wl[10 * 64 + lane], w11 = wl[11 * 64 + lane];
    const float2 w12 = wl[12 * 64 + lane], w13 = wl[13 * 64 + lane];
    const float2 w14 = wl[14 * 64 + lane], w15 = wl[15 * 64 + lane];
    const float2 bias = *reinterpret_cast<const float2*>(be + d0);

    const int beg = (n == 0) ? 0 : row_end[n - 1];
    const int end = row_end[n];

    float2 acc = *reinterpret_cast<const float2*>(h + (size_t)n * DIM + d0);

#define LOADSRC(S, IDX)                                                       \
    S = *(reinterpret_cast<const int4*>(src_csr + (IDX)) + vzero);

#define STAGE(HB, EB, IDX, S)                                                 \
    {                                                                         \
        const int s01 = hilane ? (S).y : (S).x;                               \
        const int s23 = hilane ? (S).w : (S).z;                               \
        gld_lds16(h + (size_t)s01 * DIM + lmod4, &HB[wid][0]);                \
        gld_lds16(h + (size_t)s23 * DIM + lmod4, &HB[wid][2 * DIM]);          \
        gld_lds4(ea_csr + (size_t)(IDX) * EDGE_DIM + lane, &EB[wid][0]);      \
    }

#define EF(C, WK)                                                             \
    tt.x = fmaf(C, WK.x, tt.x);                                               \
    tt.y = fmaf(C, WK.y, tt.y);

#define COMPUTE(HB, EB, IDX)                                                  \
    _Pragma("unroll")                                                         \
    for (int j = 0; j < 4; ++j) {                                             \
        const float2 hv = *reinterpret_cast<const float2*>(&HB[wid][j * DIM + d0]);        \
        const float4 a0 = *reinterpret_cast<const float4*>(&EB[wid][j * EDGE_DIM + 0]);    \
        const float4 a1 = *reinterpret_cast<const float4*>(&EB[wid][j * EDGE_DIM + 4]);    \
        const float4 a2 = *reinterpret_cast<const float4*>(&EB[wid][j * EDGE_DIM + 8]);    \
        const float4 a3 = *reinterpret_cast<const float4*>(&EB[wid][j * EDGE_DIM + 12]);   \
        float2 tt = bias;                                                     \
        EF(a0.x, w0)   EF(a0.y, w1)   EF(a0.z, w2)   EF(a0.w, w3)             \
        EF(a1.x, w4)   EF(a1.y, w5)   EF(a1.z, w6)   EF(a1.w, w7)             \
        EF(a2.x, w8)   EF(a2.y, w9)   EF(a2.z, w10)  EF(a2.w, w11)            \
        EF(a3.x, w12)  EF(a3.y, w13)  EF(a3.z, w14)  EF(a3.w, w15)            \
        const float mx = fmaxf(hv.x + tt.x, 0.0f);                            \
        const float my = fmaxf(hv.y + tt.y, 0.0f);                            \
        const bool ok = (unsigned)((IDX) + j - beg) < span;                   \
        acc.x += ok ? mx : 0.0f;                                              \
        acc.y += ok ? my : 0.0f;                                              \
    }

    if (beg < end) {
        const unsigned span = (unsigned)(end - beg);
        int idx = beg & ~3;                      // 16B-aligned batch start
        const int nb = (end - idx + 3) >> 2;
        int4 sA, sB;
        LOADSRC(sA, idx)                 // src batch 0 (one dwordx4)
        STAGE(hbA, ebA, idx, sA)         // stage batch 0 -> A
        LOADSRC(sB, idx + 4)             // src batch 1 (pad-safe)
        int i = 0;
        while (true) {
            // ---- batch i from A; stage i+1 -> B under A's compute ----
            if (i + 1 < nb) { STAGE(hbB, ebB, idx + 4, sB) }
            LOADSRC(sA, idx + 8)         // src for batch i+2 (pad-safe)
            COMPUTE(hbA, ebA, idx)
            ++i; idx += 4;
            if (i >= nb) break;
            // ---- batch i from B; stage i+1 -> A under B's compute ----
            if (i + 1 < nb) { STAGE(hbA, ebA, idx + 4, sA) }
            LOADSRC(sB, idx + 8)
            COMPUTE(hbB, ebB, idx)
            ++i; idx += 4;
            if (i >= nb) break;
        }
    }
#undef LOADSRC
#undef STAGE
#undef EF
#undef COMPUTE
    *reinterpret_cast<float2*>(z + (size_t)n * DIM + d0) = acc;
}

// ---------------------------------------------------------------------------
// Node MLP kernel (best-measured config): 64 nodes/block, 256 threads,
// acc[8][4], BK=32 W k-tiles double-buffered via global_load_lds, zt read as
// float4 along k (k4-grouping).
// ---------------------------------------------------------------------------
__global__ __launch_bounds__(256) void node_kernel(
    const float* __restrict__ zin,   // [N,128]
    const float* __restrict__ W1,    // [128,128]
    const float* __restrict__ b1,    // [128]
    const float* __restrict__ W2,    // [128,128]
    const float* __restrict__ b2,    // [128]
    float* __restrict__ hout)        // [N,128]
{
    __shared__ float zt[64 * 128];   // 32 KB
    __shared__ float wt[2][32 * 128];// 2 x 16 KB, double-buffered W k-tile

    const int t = threadIdx.x;
    const int n0 = blockIdx.x * 64;
    const int c0 = (t & 31) * 4;
    const int r0 = (t >> 5) * 8;

    // stage tile 0 (W1, k-tile 0) into wt[0] — async
#pragma unroll
    for (int i = 0; i < 4; ++i) {
        const int f = (i * 256 + t) * 4;
        gld_lds16(W1 + f, &wt[0][f]);
    }

    // load z tile (coalesced float4)
#pragma unroll
    for (int i = 0; i < 8; ++i) {
        const int f = (i * 256 + t) * 4;
        const int node = n0 + (f >> 7);
        const int dim = f & 127;
        float4 v = make_float4(0.f, 0.f, 0.f, 0.f);
        if (node < N_NODES)
            v = *reinterpret_cast<const float4*>(zin + (size_t)node * DIM + dim);
        *reinterpret_cast<float4*>(&zt[f]) = v;
    }

    const float4 bb1 = *reinterpret_cast<const float4*>(b1 + c0);
    const float4 bb2 = *reinterpret_cast<const float4*>(b2 + c0);

    float acc[8][4];
#pragma unroll
    for (int i = 0; i < 8; ++i)
#pragma unroll
        for (int j = 0; j < 4; ++j) acc[i][j] = 0.0f;

    __syncthreads();   // wt[0] DMA drained + zt visible

    // tiles tt = 0..7: W1 k-tiles 0..3, then W2 k-tiles 0..3
    for (int tt = 0; tt < 8; ++tt) {
        if (tt < 7) {
            const float* Wp = (tt + 1 < 4) ? W1 : W2;
            const int nk = (tt + 1) & 3;
            const int nb = (tt + 1) & 1;
#pragma unroll
            for (int i = 0; i < 4; ++i) {
                const int f = (i * 256 + t) * 4;
                gld_lds16(Wp + nk * 4096 + f, &wt[nb][f]);
            }
        }

        const int kk = tt & 3;
        const float* wts = wt[tt & 1];
#pragma unroll
        for (int k4 = 0; k4 < 8; ++k4) {
            const int kb = kk * 32 + k4 * 4;
            const float4 wv0 = *reinterpret_cast<const float4*>(&wts[(k4 * 4 + 0) * 128 + c0]);
            const float4 wv1 = *reinterpret_cast<const float4*>(&wts[(k4 * 4 + 1) * 128 + c0]);
            const float4 wv2 = *reinterpret_cast<const float4*>(&wts[(k4 * 4 + 2) * 128 + c0]);
            const float4 wv3 = *reinterpret_cast<const float4*>(&wts[(k4 * 4 + 3) * 128 + c0]);
#pragma unroll
            for (int i = 0; i < 8; ++i) {
                const float4 zv = *reinterpret_cast<const float4*>(&zt[(r0 + i) * 128 + kb]);
                acc[i][0] = fmaf(zv.x, wv0.x, acc[i][0]);
                acc[i][1] = fmaf(zv.x, wv0.y, acc[i][1]);
                acc[i][2] = fmaf(zv.x, wv0.z, acc[i][2]);
                acc[i][3] = fmaf(zv.x, wv0.w, acc[i][3]);
                acc[i][0] = fmaf(zv.y, wv1.x, acc[i][0]);
                acc[i][1] = fmaf(zv.y, wv1.y, acc[i][1]);
                acc[i][2] = fmaf(zv.y, wv1.z, acc[i][2]);
                acc[i][3] = fmaf(zv.y, wv1.w, acc[i][3]);
                acc[i][0] = fmaf(zv.z, wv2.x, acc[i][0]);
                acc[i][1] = fmaf(zv.z, wv2.y, acc[i][1]);
                acc[i][2] = fmaf(zv.z, wv2.z, acc[i][2]);
                acc[i][3] = fmaf(zv.z, wv2.w, acc[i][3]);
                acc[i][0] = fmaf(zv.w, wv3.x, acc[i][0]);
                acc[i][1] = fmaf(zv.w, wv3.y, acc[i][1]);
                acc[i][2] = fmaf(zv.w, wv3.z, acc[i][2]);
                acc[i][3] = fmaf(zv.w, wv3.w, acc[i][3]);
            }
        }
        __syncthreads();   // next tile landed; all reads of this phase done

        if (tt == 3) {
#pragma unroll
            for (int i = 0; i < 8; ++i) {
                float4 v = make_float4(fmaxf(acc[i][0] + bb1.x, 0.f),
                                       fmaxf(acc[i][1] + bb1.y, 0.f),
                                       fmaxf(acc[i][2] + bb1.z, 0.f),
                                       fmaxf(acc[i][3] + bb1.w, 0.f));
                *reinterpret_cast<float4*>(&zt[(r0 + i) * 128 + c0]) = v;
#pragma unroll
                for (int j = 0; j < 4; ++j) acc[i][j] = 0.0f;
            }
            __syncthreads();   // new zt visible before stage-2 compute
        }
    }

    // epilogue: h = relu(acc + b2)
#pragma unroll
    for (int i = 0; i < 8; ++i) {
        const int node = n0 + r0 + i;
        if (node < N_NODES) {
            float4 v = make_float4(fmaxf(acc[i][0] + bb2.x, 0.f),
                                   fmaxf(acc[i][1] + bb2.y, 0.f),
                                   fmaxf(acc[i][2] + bb2.z, 0.f),
                                   fmaxf(acc[i][3] + bb2.w, 0.f));
            *reinterpret_cast<float4*>(hout + (size_t)node * DIM + c0) = v;
        }
    }
}

// ---------------------------------------------------------------------------
// Pool: batch is SORTED -> run-length accumulate, one atomic set per run.
// ---------------------------------------------------------------------------
__global__ __launch_bounds__(256) void pool_kernel(
    const float* __restrict__ h, const int* __restrict__ batch,
    float* __restrict__ gsum, float* __restrict__ cnt)
{
    const int lane = threadIdx.x & 63;
    const int wave = blockIdx.x * (blockDim.x >> 6) + (threadIdx.x >> 6);
    const int n0 = wave * 64;
    if (n0 >= N_NODES) return;
    const int n1 = min(n0 + 64, N_NODES);
    const int d0 = 2 * lane;

    int gcur = batch[n0];
    float2 acc = make_float2(0.f, 0.f);
    float c = 0.f;
    for (int n = n0; n < n1; ++n) {
        const int b = batch[n];
        if (b != gcur) {
            atomicAdd(&gsum[gcur * DIM + d0], acc.x);
            atomicAdd(&gsum[gcur * DIM + d0 + 1], acc.y);
            if (lane == 0) atomicAdd(&cnt[gcur], c);
            gcur = b; acc = make_float2(0.f, 0.f); c = 0.f;
        }
        const float2 hv = *reinterpret_cast<const float2*>(h + (size_t)n * DIM + d0);
        acc.x += hv.x; acc.y += hv.y; c += 1.f;
    }
    atomicAdd(&gsum[gcur * DIM + d0], acc.x);
    atomicAdd(&gsum[gcur * DIM + d0 + 1], acc.y);
    if (lane == 0) atomicAdd(&cnt[gcur], c);
}

// ---------------------------------------------------------------------------
// Readout: out[g] = relu(mean_g @ Wh1 + bh1) @ Wh2 + bh2.
// ---------------------------------------------------------------------------
__global__ __launch_bounds__(128) void readout_kernel(
    const float* __restrict__ gsum, const float* __restrict__ cnt,
    const float* __restrict__ Wh1, const float* __restrict__ bh1,
    const float* __restrict__ Wh2, const float* __restrict__ bh2,
    float* __restrict__ out)
{
    __shared__ float gv[128];
    __shared__ float partial[2];
    const int g = blockIdx.x;
    const int t = threadIdx.x;
    const float c = fmaxf(cnt[g], 1.0f);
    gv[t] = gsum[g * DIM + t] / c;
    __syncthreads();
    float acc = bh1[t];
    for (int k = 0; k < DIM; ++k)
        acc = fmaf(gv[k], Wh1[k * DIM + t], acc);
    float tv = fmaxf(acc, 0.0f) * Wh2[t];
    for (int off = 32; off > 0; off >>= 1) tv += __shfl_down(tv, off);
    if ((t & 63) == 0) partial[t >> 6] = tv;
    __syncthreads();
    if (t == 0) out[g] = partial[0] + partial[1] + bh2[0];
}

// ---------------------------------------------------------------------------
extern "C" void kernel_launch(void* const* d_in, const int* in_sizes, int n_in,
                              void* d_out, int out_size, void* d_ws, size_t ws_size,
                              hipStream_t stream) {
    const float* x         = (const float*)d_in[0];
    const int*   edge_idx  = (const int*)d_in[1];
    const int*   batch     = (const int*)d_in[2];
    const float* edge_attr = (const float*)d_in[3];
    const float* W1        = (const float*)d_in[4];
    const float* b1        = (const float*)d_in[5];
    const float* W2        = (const float*)d_in[6];
    const float* b2        = (const float*)d_in[7];
    const float* We        = (const float*)d_in[8];
    const float* be        = (const float*)d_in[9];
    const float* Wh1       = (const float*)d_in[10];
    const float* bh1       = (const float*)d_in[11];
    const float* Wh2       = (const float*)d_in[12];
    const float* bh2       = (const float*)d_in[13];
    float* out = (float*)d_out;

    const int* src = edge_idx;            // edge_index[0]
    const int* dst = edge_idx + N_EDGES;  // edge_index[1]

    float* ws = (float*)d_ws;
    float* h_ws    = ws;                                       // 50000*128 f
    float* z_ws    = h_ws + (size_t)N_NODES * DIM;             // 50000*128 f
    float* ea_csr  = z_ws + (size_t)N_NODES * DIM;             // (800000+8)*16 f
    float* gsum    = ea_csr + (size_t)(N_EDGES + 8) * EDGE_DIM;// 64*128 f
    float* cntf    = gsum + (size_t)N_GRAPHS * DIM;            // 64 f
    int*   row_ptr = (int*)(cntf + N_GRAPHS);                  // 50004 i (padded)
    int*   src_csr = row_ptr + (N_NODES + 4);                  // 800016 i, 16B-aligned

    // ---- CSR build (once per launch; reused by all 3 layers) ----
    hipMemsetAsync(row_ptr, 0, (N_NODES + 1) * sizeof(int), stream);
    hist_kernel<<<(N_EDGES + 255) / 256, 256, 0, stream>>>(dst, row_ptr);
    scan_kernel<<<1, 1024, 0, stream>>>(row_ptr);
    scatter_kernel<<<(N_EDGES + 255) / 256, 256, 0, stream>>>(
        dst, src, edge_attr, row_ptr, src_csr, ea_csr);

    // ---- layers ----
    const float* hin = x;
    for (int l = 0; l < N_LAYERS; ++l) {
        gather_kernel<<<(N_NODES + 3) / 4, 256, 0, stream>>>(
            hin, ea_csr, src_csr, row_ptr,
            We + (size_t)l * EDGE_DIM * DIM, be + (size_t)l * DIM, z_ws);
        node_kernel<<<(N_NODES + 63) / 64, 256, 0, stream>>>(
            z_ws,
            W1 + (size_t)l * DIM * DIM, b1 + (size_t)l * DIM,
            W2 + (size_t)l * DIM * DIM, b2 + (size_t)l * DIM,
            h_ws);
        hin = h_ws;
    }

    // ---- pool + readout ----
    hipMemsetAsync(gsum, 0, ((size_t)N_GRAPHS * DIM + N_GRAPHS) * sizeof(float), stream);
    pool_kernel<<<(N_NODES + 64 * 4 - 1) / (64 * 4), 256, 0, stream>>>(h_ws, batch, gsum, cntf);
    readout_kernel<<<N_GRAPHS, 128, 0, stream>>>(gsum, cntf, Wh1, bh1, Wh2, bh2, out);
}